// Round 1
// baseline (425.188 us; speedup 1.0000x reference)
//
#include <hip/hip_runtime.h>
#include <hip/hip_bf16.h>

#define DEVI __device__ __forceinline__

typedef __attribute__((ext_vector_type(8))) short bf16x8;
typedef __attribute__((ext_vector_type(4))) float f32x4;
typedef unsigned short u16;

static constexpr float SCALE = 0.03125f;   // 1/sqrt(1024)

DEVI u16 f2bf(float f){
    __hip_bfloat16 h = __float2bfloat16(f);
    return __builtin_bit_cast(u16, h);
}

DEVI void gload16(const void* g, void* l){
    // async global->LDS, 16B per lane; LDS dest = wave-uniform base + lane*16
    __builtin_amdgcn_global_load_lds(
        (const __attribute__((address_space(1))) void*)g,
        (__attribute__((address_space(3))) void*)l,
        16, 0, 0);
}

// ---------------- fp32 -> bf16 bulk convert ----------------
__global__ __launch_bounds__(256) void k_cvt(const float* __restrict__ src,
                                             u16* __restrict__ dst, int n8){
    int stride = gridDim.x * blockDim.x;
    for (int i = blockIdx.x * blockDim.x + threadIdx.x; i < n8; i += stride){
        float4 a = *(const float4*)(src + (size_t)i*8);
        float4 b = *(const float4*)(src + (size_t)i*8 + 4);
        uint4 o;
        o.x = f2bf(a.x) | ((unsigned)f2bf(a.y) << 16);
        o.y = f2bf(a.z) | ((unsigned)f2bf(a.w) << 16);
        o.z = f2bf(b.x) | ((unsigned)f2bf(b.y) << 16);
        o.w = f2bf(b.z) | ((unsigned)f2bf(b.w) << 16);
        *(uint4*)(dst + (size_t)i*8) = o;
    }
}

// ---------------- 128x128 NT GEMM (m97-style), C = A * B^T ----------------
// A: [M][K] bf16 K-major, Bm: [N][K] bf16 K-major.
// EPI 0: fp32 store to Cf[M][N].  EPI 1: QKV scatter to qh/kh (head-split) and vT (transposed).
template<int EPI>
__global__ __launch_bounds__(256) void k_gemm(
    const u16* __restrict__ A, const u16* __restrict__ Bm,
    float* __restrict__ Cf, u16* __restrict__ qh, u16* __restrict__ kh, u16* __restrict__ vT,
    int K, int N)
{
    __shared__ __align__(16) u16 As[128*32];
    __shared__ __align__(16) u16 Bs[128*32];
    const int lane = threadIdx.x & 63, wid = threadIdx.x >> 6;

    // XCD-aware bijective swizzle (nwg % 8 == 0 in all our launches)
    const int nbx = gridDim.x;
    const int nwg = nbx * gridDim.y;
    const int bid = blockIdx.y * nbx + blockIdx.x;
    const int swz = (bid & 7) * (nwg >> 3) + (bid >> 3);
    const int rowTile = (swz / nbx) * 128;
    const int colTile = (swz % nbx) * 128;

    const int wr = wid >> 1, wc = wid & 1;
    const int lrow = lane >> 2, lch = lane & 3;

    f32x4 acc[4][4] = {};

    for (int k0 = 0; k0 < K; k0 += 32){
        __syncthreads();                       // prior LDS reads done
        #pragma unroll
        for (int cc = 0; cc < 2; ++cc){
            int c = wid*2 + cc;
            int row = c*16 + lrow;
            gload16(A + (size_t)(rowTile + row)*K + k0 + lch*8, (char*)As + c*1024);
            gload16(Bm + (size_t)(colTile + row)*K + k0 + lch*8, (char*)Bs + c*1024);
        }
        __syncthreads();                       // vmcnt drained by compiler before barrier
        bf16x8 af[4], bfr[4];
        #pragma unroll
        for (int mi = 0; mi < 4; ++mi){
            int row = wr*64 + mi*16 + (lane & 15);
            af[mi] = *(const bf16x8*)((const char*)As + row*64 + (lane>>4)*16);
        }
        #pragma unroll
        for (int nj = 0; nj < 4; ++nj){
            int row = wc*64 + nj*16 + (lane & 15);
            bfr[nj] = *(const bf16x8*)((const char*)Bs + row*64 + (lane>>4)*16);
        }
        #pragma unroll
        for (int mi = 0; mi < 4; ++mi)
            #pragma unroll
            for (int nj = 0; nj < 4; ++nj)
                acc[mi][nj] = __builtin_amdgcn_mfma_f32_16x16x32_bf16(af[mi], bfr[nj], acc[mi][nj], 0,0,0);
    }

    #pragma unroll
    for (int mi = 0; mi < 4; ++mi)
        #pragma unroll
        for (int nj = 0; nj < 4; ++nj)
            #pragma unroll
            for (int j = 0; j < 4; ++j){
                int row = rowTile + wr*64 + mi*16 + (lane>>4)*4 + j;
                int col = colTile + wc*64 + nj*16 + (lane & 15);
                if (EPI == 0){
                    Cf[(size_t)row*N + col] = acc[mi][nj][j];
                } else {
                    int b = row >> 11, srow = row & 2047;
                    u16 val = f2bf(acc[mi][nj][j]);
                    if (col < 1024){
                        int h = col >> 6, dh = col & 63;
                        qh[((size_t)((b<<4)+h)*2048 + srow)*64 + dh] = val;
                    } else if (col < 2048){
                        int c2 = col - 1024; int h = c2 >> 6, dh = c2 & 63;
                        kh[((size_t)((b<<4)+h)*2048 + srow)*64 + dh] = val;
                    } else {
                        int c2 = col - 2048; int h = c2 >> 6, dh = c2 & 63;
                        vT[((size_t)((b<<4)+h)*64 + dh)*2048 + srow] = val;
                    }
                }
            }
}

// ---------------- Pass A: recipZ[bh][k] = 1 / sum_q exp(SCALE * k.q) ----------------
// grid (16 kblocks, 64 heads), 256 thr. Wave w owns k rows [w*32, w*32+32).
__global__ __launch_bounds__(256) void k_passA(
    const u16* __restrict__ qh, const u16* __restrict__ kh, float* __restrict__ recipZ)
{
    __shared__ __align__(16) u16 k_lds[128*64];   // [128 k][64 dh], 128B rows, XOR-swizzled
    __shared__ __align__(16) u16 q_lds[128*64];
    const int lane = threadIdx.x & 63, wid = threadIdx.x >> 6;
    const int kb = blockIdx.x, bh = blockIdx.y;

    // stage k block once (pre-swizzled source, linear LDS dest)
    #pragma unroll
    for (int cc = 0; cc < 4; ++cc){
        int c = wid*4 + cc;
        int row = c*8 + (lane>>3);
        int inner = (lane&7)*16;
        gload16((const char*)(kh + ((size_t)bh*2048 + kb*128 + row)*64) + (inner ^ ((row&7)<<4)),
                (char*)k_lds + c*1024);
    }

    f32x4 sums[2] = {};
    bf16x8 ak[2][2];

    for (int qt = 0; qt < 16; ++qt){
        __syncthreads();   // prior q_lds reads done (also drains k-stage at qt=0)
        #pragma unroll
        for (int cc = 0; cc < 4; ++cc){
            int c = wid*4 + cc;
            int row = c*8 + (lane>>3);
            int inner = (lane&7)*16;
            gload16((const char*)(qh + ((size_t)bh*2048 + qt*128 + row)*64) + (inner ^ ((row&7)<<4)),
                    (char*)q_lds + c*1024);
        }
        __syncthreads();
        if (qt == 0){
            #pragma unroll
            for (int mi = 0; mi < 2; ++mi)
                #pragma unroll
                for (int kk = 0; kk < 2; ++kk){
                    int row = wid*32 + mi*16 + (lane & 15);
                    ak[mi][kk] = *(const bf16x8*)((const char*)k_lds + row*128
                                  + ((kk*64 + (lane>>4)*16) ^ ((row&7)<<4)));
                }
        }
        #pragma unroll
        for (int nj = 0; nj < 8; ++nj){
            int row = nj*16 + (lane & 15);
            int base = row*128, sw = (row&7)<<4;
            bf16x8 bq0 = *(const bf16x8*)((const char*)q_lds + base + (((lane>>4)*16) ^ sw));
            bf16x8 bq1 = *(const bf16x8*)((const char*)q_lds + base + ((64 + (lane>>4)*16) ^ sw));
            #pragma unroll
            for (int mi = 0; mi < 2; ++mi){
                f32x4 z = {};
                z = __builtin_amdgcn_mfma_f32_16x16x32_bf16(ak[mi][0], bq0, z, 0,0,0);
                z = __builtin_amdgcn_mfma_f32_16x16x32_bf16(ak[mi][1], bq1, z, 0,0,0);
                #pragma unroll
                for (int j = 0; j < 4; ++j) sums[mi][j] += __expf(z[j] * SCALE);
            }
        }
    }
    #pragma unroll
    for (int mi = 0; mi < 2; ++mi)
        #pragma unroll
        for (int j = 0; j < 4; ++j){
            float v = sums[mi][j];
            v += __shfl_xor(v, 1); v += __shfl_xor(v, 2);
            v += __shfl_xor(v, 4); v += __shfl_xor(v, 8);
            if ((lane & 15) == 0){
                int krow = kb*128 + wid*32 + mi*16 + (lane>>4)*4 + j;
                recipZ[(size_t)bh*2048 + krow] = 1.0f / v;
            }
        }
}

// ---------------- Pass B: out[q,d] = sum_k exp(SCALE*q.k) * recipZ[k] * v[k,d] ----------------
// grid (16 qblocks, 64 heads), 256 thr. Wave w owns q rows [w*32, w*32+32).
__global__ __launch_bounds__(256) void k_passB(
    const u16* __restrict__ qh, const u16* __restrict__ kh, const u16* __restrict__ vT,
    const float* __restrict__ recipZ, u16* __restrict__ Zbf)
{
    __shared__ __align__(16) u16 q_lds[128*64];   // 16KB
    __shared__ __align__(16) u16 k_lds[128*64];   // 16KB
    __shared__ __align__(16) u16 v_lds[64*128];   // 16KB  [64 d][128 k], 256B rows
    __shared__ __align__(16) u16 p_lds[128*128];  // 32KB  [128 q][128 k], 256B rows
    const int lane = threadIdx.x & 63, wid = threadIdx.x >> 6;
    const int qb = blockIdx.x, bh = blockIdx.y;

    // stage q block once
    #pragma unroll
    for (int cc = 0; cc < 4; ++cc){
        int c = wid*4 + cc;
        int row = c*8 + (lane>>3);
        int inner = (lane&7)*16;
        gload16((const char*)(qh + ((size_t)bh*2048 + qb*128 + row)*64) + (inner ^ ((row&7)<<4)),
                (char*)q_lds + c*1024);
    }

    f32x4 acc[2][4] = {};
    bf16x8 aq[2][2];

    for (int kt = 0; kt < 16; ++kt){
        __syncthreads();   // prior reads of k_lds/v_lds/p_lds done
        #pragma unroll
        for (int cc = 0; cc < 4; ++cc){
            int c = wid*4 + cc;
            int row = c*8 + (lane>>3);
            int inner = (lane&7)*16;
            gload16((const char*)(kh + ((size_t)bh*2048 + kt*128 + row)*64) + (inner ^ ((row&7)<<4)),
                    (char*)k_lds + c*1024);
        }
        #pragma unroll
        for (int cc = 0; cc < 4; ++cc){
            int c = wid*4 + cc;
            int d = c*4 + (lane>>4);
            int inner = (lane&15)*16;
            gload16((const char*)(vT + ((size_t)bh*64 + d)*2048 + kt*128) + (inner ^ ((d&7)<<4)),
                    (char*)v_lds + c*1024);
        }
        __syncthreads();
        if (kt == 0){
            #pragma unroll
            for (int mi = 0; mi < 2; ++mi)
                #pragma unroll
                for (int kk = 0; kk < 2; ++kk){
                    int row = wid*32 + mi*16 + (lane & 15);
                    aq[mi][kk] = *(const bf16x8*)((const char*)q_lds + row*128
                                  + ((kk*64 + (lane>>4)*16) ^ ((row&7)<<4)));
                }
        }
        // score -> p (bf16, swizzled p_lds)
        #pragma unroll
        for (int nj = 0; nj < 8; ++nj){
            int krow = nj*16 + (lane & 15);
            int base = krow*128, sw = (krow&7)<<4;
            bf16x8 bk0 = *(const bf16x8*)((const char*)k_lds + base + (((lane>>4)*16) ^ sw));
            bf16x8 bk1 = *(const bf16x8*)((const char*)k_lds + base + ((64 + (lane>>4)*16) ^ sw));
            float rz = recipZ[(size_t)bh*2048 + kt*128 + krow];
            #pragma unroll
            for (int mi = 0; mi < 2; ++mi){
                f32x4 z = {};
                z = __builtin_amdgcn_mfma_f32_16x16x32_bf16(aq[mi][0], bk0, z, 0,0,0);
                z = __builtin_amdgcn_mfma_f32_16x16x32_bf16(aq[mi][1], bk1, z, 0,0,0);
                #pragma unroll
                for (int j = 0; j < 4; ++j){
                    float p = __expf(z[j] * SCALE) * rz;
                    int prow = wid*32 + mi*16 + (lane>>4)*4 + j;
                    int pcol = nj*16 + (lane & 15);
                    *(u16*)((char*)p_lds + prow*256 + ((pcol*2) ^ ((prow&7)<<4))) = f2bf(p);
                }
            }
        }
        __syncthreads();
        // PV
        #pragma unroll
        for (int kk = 0; kk < 4; ++kk){
            bf16x8 ap[2], bv[4];
            #pragma unroll
            for (int mi = 0; mi < 2; ++mi){
                int row = wid*32 + mi*16 + (lane & 15);
                ap[mi] = *(const bf16x8*)((const char*)p_lds + row*256
                           + ((kk*64 + (lane>>4)*16) ^ ((row&7)<<4)));
            }
            #pragma unroll
            for (int nj = 0; nj < 4; ++nj){
                int d = nj*16 + (lane & 15);
                bv[nj] = *(const bf16x8*)((const char*)v_lds + d*256
                           + ((kk*64 + (lane>>4)*16) ^ ((d&7)<<4)));
            }
            #pragma unroll
            for (int mi = 0; mi < 2; ++mi)
                #pragma unroll
                for (int nj = 0; nj < 4; ++nj)
                    acc[mi][nj] = __builtin_amdgcn_mfma_f32_16x16x32_bf16(ap[mi], bv[nj], acc[mi][nj], 0,0,0);
        }
    }
    // epilogue -> merged-head bf16 [b*2048+q][h*64+d]
    const int b = bh >> 4, h = bh & 15;
    #pragma unroll
    for (int mi = 0; mi < 2; ++mi)
        #pragma unroll
        for (int nj = 0; nj < 4; ++nj)
            #pragma unroll
            for (int j = 0; j < 4; ++j){
                int qrow = qb*128 + wid*32 + mi*16 + (lane>>4)*4 + j;
                int d = nj*16 + (lane & 15);
                Zbf[((size_t)b*2048 + qrow)*1024 + h*64 + d] = f2bf(acc[mi][nj][j]);
            }
}

extern "C" void kernel_launch(void* const* d_in, const int* in_sizes, int n_in,
                              void* d_out, int out_size, void* d_ws, size_t ws_size,
                              hipStream_t stream)
{
    const float* x  = (const float*)d_in[0];
    const float* Wq = (const float*)d_in[1];
    const float* Wk = (const float*)d_in[2];
    const float* Wv = (const float*)d_in[3];
    const float* Wo = (const float*)d_in[4];

    char* ws = (char*)d_ws;
    u16*   xbf  = (u16*)ws;                       // 16 MB [8192][1024]; reused later as Zbf
    u16*   wqkv = (u16*)(ws + (16u<<20));         //  6 MB [3072][1024] (Wq|Wk|Wv rows)
    u16*   wobf = (u16*)(ws + (22u<<20));         //  2 MB [1024][1024]
    u16*   vT   = (u16*)(ws + (24u<<20));         // 16 MB [64 bh][64 dh][2048 s]
    float* rZ   = (float*)(ws + (40u<<20));       // 0.5 MB [64][2048]
    u16*   Zbf  = xbf;                            // x dead after QKV GEMM

    // q,k head-split tensors live in d_out (32 MB) — dead before final GEMM writes it
    u16* qh = (u16*)d_out;                        // 16 MB [64 bh][2048 s][64 dh]
    u16* kh = (u16*)d_out + (size_t)8192*1024;    // 16 MB

    // fp32 -> bf16
    k_cvt<<<1024, 256, 0, stream>>>(x,  xbf,  8192*1024/8);
    k_cvt<<<256,  256, 0, stream>>>(Wq, wqkv,               1024*1024/8);
    k_cvt<<<256,  256, 0, stream>>>(Wk, wqkv + 1024*1024,   1024*1024/8);
    k_cvt<<<256,  256, 0, stream>>>(Wv, wqkv + 2*1024*1024, 1024*1024/8);
    k_cvt<<<256,  256, 0, stream>>>(Wo, wobf,               1024*1024/8);

    // QKV projection (fused): [8192][1024] x [3072][1024]^T
    k_gemm<1><<<dim3(24, 64), 256, 0, stream>>>(xbf, wqkv, nullptr, qh, kh, vT, 1024, 3072);

    // Pass A: per-key softmax denominators over queries
    k_passA<<<dim3(16, 64), 256, 0, stream>>>(qh, kh, rZ);

    // Pass B: fused QK^T -> scale -> PV
    k_passB<<<dim3(16, 64), 256, 0, stream>>>(qh, kh, vT, rZ, Zbf);

    // Output projection: [8192][1024] x [1024][1024]^T -> fp32 d_out
    k_gemm<0><<<dim3(8, 64), 256, 0, stream>>>(Zbf, wobf, (float*)d_out,
                                               nullptr, nullptr, nullptr, 1024, 1024);
}

// Round 2
// 396.197 us; speedup vs baseline: 1.0732x; 1.0732x over previous
//
#include <hip/hip_runtime.h>
#include <hip/hip_bf16.h>

#define DEVI __device__ __forceinline__

typedef __attribute__((ext_vector_type(8))) short bf16x8;
typedef __attribute__((ext_vector_type(4))) float f32x4;
typedef unsigned short u16;

static constexpr float SCALE = 0.03125f;   // 1/sqrt(1024)

DEVI u16 f2bf(float f){
    __hip_bfloat16 h = __float2bfloat16(f);
    return __builtin_bit_cast(u16, h);
}
DEVI float bf2f(u16 h){
    unsigned u = ((unsigned)h) << 16;
    return __builtin_bit_cast(float, u);
}

DEVI void gload16(const void* g, void* l){
    __builtin_amdgcn_global_load_lds(
        (const __attribute__((address_space(1))) void*)g,
        (__attribute__((address_space(3))) void*)l,
        16, 0, 0);
}

// permlane swaps (gfx950): both outputs used
DEVI void plswap32(unsigned &a, unsigned &b){
#if defined(__has_builtin) && __has_builtin(__builtin_amdgcn_permlane32_swap)
    typedef unsigned uv2 __attribute__((ext_vector_type(2)));
    uv2 r = __builtin_amdgcn_permlane32_swap(a, b, false, false);
    a = r[0]; b = r[1];
#else
    asm("v_permlane32_swap_b32 %0, %1" : "+v"(a), "+v"(b));
#endif
}
DEVI void plswap16(unsigned &a, unsigned &b){
#if defined(__has_builtin) && __has_builtin(__builtin_amdgcn_permlane16_swap)
    typedef unsigned uv2 __attribute__((ext_vector_type(2)));
    uv2 r = __builtin_amdgcn_permlane16_swap(a, b, false, false);
    a = r[0]; b = r[1];
#else
    asm("v_permlane16_swap_b32 %0, %1" : "+v"(a), "+v"(b));
#endif
}

// ---------------- fp32 -> bf16 bulk convert ----------------
__global__ __launch_bounds__(256) void k_cvt(const float* __restrict__ src,
                                             u16* __restrict__ dst, int n8){
    int stride = gridDim.x * blockDim.x;
    for (int i = blockIdx.x * blockDim.x + threadIdx.x; i < n8; i += stride){
        float4 a = *(const float4*)(src + (size_t)i*8);
        float4 b = *(const float4*)(src + (size_t)i*8 + 4);
        uint4 o;
        o.x = f2bf(a.x) | ((unsigned)f2bf(a.y) << 16);
        o.y = f2bf(a.z) | ((unsigned)f2bf(a.w) << 16);
        o.z = f2bf(b.x) | ((unsigned)f2bf(b.y) << 16);
        o.w = f2bf(b.z) | ((unsigned)f2bf(b.w) << 16);
        *(uint4*)(dst + (size_t)i*8) = o;
    }
}

// ---------------- 128x128 NT GEMM (m97-style), C = A * B^T ----------------
template<int EPI>
__global__ __launch_bounds__(256) void k_gemm(
    const u16* __restrict__ A, const u16* __restrict__ Bm,
    float* __restrict__ Cf, u16* __restrict__ qh, u16* __restrict__ kh, u16* __restrict__ vT,
    int K, int N)
{
    __shared__ __align__(16) u16 As[128*32];
    __shared__ __align__(16) u16 Bs[128*32];
    const int lane = threadIdx.x & 63, wid = threadIdx.x >> 6;

    const int nbx = gridDim.x;
    const int nwg = nbx * gridDim.y;
    const int bid = blockIdx.y * nbx + blockIdx.x;
    const int swz = (bid & 7) * (nwg >> 3) + (bid >> 3);
    const int rowTile = (swz / nbx) * 128;
    const int colTile = (swz % nbx) * 128;

    const int wr = wid >> 1, wc = wid & 1;
    const int lrow = lane >> 2, lch = lane & 3;

    f32x4 acc[4][4] = {};

    for (int k0 = 0; k0 < K; k0 += 32){
        __syncthreads();
        #pragma unroll
        for (int cc = 0; cc < 2; ++cc){
            int c = wid*2 + cc;
            int row = c*16 + lrow;
            gload16(A + (size_t)(rowTile + row)*K + k0 + lch*8, (char*)As + c*1024);
            gload16(Bm + (size_t)(colTile + row)*K + k0 + lch*8, (char*)Bs + c*1024);
        }
        __syncthreads();
        bf16x8 af[4], bfr[4];
        #pragma unroll
        for (int mi = 0; mi < 4; ++mi){
            int row = wr*64 + mi*16 + (lane & 15);
            af[mi] = *(const bf16x8*)((const char*)As + row*64 + (lane>>4)*16);
        }
        #pragma unroll
        for (int nj = 0; nj < 4; ++nj){
            int row = wc*64 + nj*16 + (lane & 15);
            bfr[nj] = *(const bf16x8*)((const char*)Bs + row*64 + (lane>>4)*16);
        }
        #pragma unroll
        for (int mi = 0; mi < 4; ++mi)
            #pragma unroll
            for (int nj = 0; nj < 4; ++nj)
                acc[mi][nj] = __builtin_amdgcn_mfma_f32_16x16x32_bf16(af[mi], bfr[nj], acc[mi][nj], 0,0,0);
    }

    #pragma unroll
    for (int mi = 0; mi < 4; ++mi)
        #pragma unroll
        for (int nj = 0; nj < 4; ++nj)
            #pragma unroll
            for (int j = 0; j < 4; ++j){
                int row = rowTile + wr*64 + mi*16 + (lane>>4)*4 + j;
                int col = colTile + wc*64 + nj*16 + (lane & 15);
                if (EPI == 0){
                    Cf[(size_t)row*N + col] = acc[mi][nj][j];
                } else {
                    int b = row >> 11, srow = row & 2047;
                    u16 val = f2bf(acc[mi][nj][j]);
                    if (col < 1024){
                        int h = col >> 6, dh = col & 63;
                        qh[((size_t)((b<<4)+h)*2048 + srow)*64 + dh] = val;
                    } else if (col < 2048){
                        int c2 = col - 1024; int h = c2 >> 6, dh = c2 & 63;
                        kh[((size_t)((b<<4)+h)*2048 + srow)*64 + dh] = val;
                    } else {
                        int c2 = col - 2048; int h = c2 >> 6, dh = c2 & 63;
                        vT[((size_t)((b<<4)+h)*64 + dh)*2048 + srow] = val;
                    }
                }
            }
}

// ---------------- Pass A: recipZ[bh][k] = 1 / sum_q exp(SCALE * k.q) ----------------
__global__ __launch_bounds__(256) void k_passA(
    const u16* __restrict__ qh, const u16* __restrict__ kh, float* __restrict__ recipZ)
{
    __shared__ __align__(16) u16 k_lds[128*64];
    __shared__ __align__(16) u16 q_lds[128*64];
    const int lane = threadIdx.x & 63, wid = threadIdx.x >> 6;
    const int kb = blockIdx.x, bh = blockIdx.y;

    #pragma unroll
    for (int cc = 0; cc < 4; ++cc){
        int c = wid*4 + cc;
        int row = c*8 + (lane>>3);
        int inner = (lane&7)*16;
        gload16((const char*)(kh + ((size_t)bh*2048 + kb*128 + row)*64) + (inner ^ ((row&7)<<4)),
                (char*)k_lds + c*1024);
    }

    f32x4 sums[2] = {};
    bf16x8 ak[2][2];

    for (int qt = 0; qt < 16; ++qt){
        __syncthreads();
        #pragma unroll
        for (int cc = 0; cc < 4; ++cc){
            int c = wid*4 + cc;
            int row = c*8 + (lane>>3);
            int inner = (lane&7)*16;
            gload16((const char*)(qh + ((size_t)bh*2048 + qt*128 + row)*64) + (inner ^ ((row&7)<<4)),
                    (char*)q_lds + c*1024);
        }
        __syncthreads();
        if (qt == 0){
            #pragma unroll
            for (int mi = 0; mi < 2; ++mi)
                #pragma unroll
                for (int kk = 0; kk < 2; ++kk){
                    int row = wid*32 + mi*16 + (lane & 15);
                    ak[mi][kk] = *(const bf16x8*)((const char*)k_lds + row*128
                                  + ((kk*64 + (lane>>4)*16) ^ ((row&7)<<4)));
                }
        }
        #pragma unroll
        for (int nj = 0; nj < 8; ++nj){
            int row = nj*16 + (lane & 15);
            int base = row*128, sw = (row&7)<<4;
            bf16x8 bq0 = *(const bf16x8*)((const char*)q_lds + base + (((lane>>4)*16) ^ sw));
            bf16x8 bq1 = *(const bf16x8*)((const char*)q_lds + base + ((64 + (lane>>4)*16) ^ sw));
            #pragma unroll
            for (int mi = 0; mi < 2; ++mi){
                f32x4 z = {};
                z = __builtin_amdgcn_mfma_f32_16x16x32_bf16(ak[mi][0], bq0, z, 0,0,0);
                z = __builtin_amdgcn_mfma_f32_16x16x32_bf16(ak[mi][1], bq1, z, 0,0,0);
                #pragma unroll
                for (int j = 0; j < 4; ++j) sums[mi][j] += __expf(z[j] * SCALE);
            }
        }
    }
    #pragma unroll
    for (int mi = 0; mi < 2; ++mi)
        #pragma unroll
        for (int j = 0; j < 4; ++j){
            float v = sums[mi][j];
            v += __shfl_xor(v, 1); v += __shfl_xor(v, 2);
            v += __shfl_xor(v, 4); v += __shfl_xor(v, 8);
            if ((lane & 15) == 0){
                int krow = kb*128 + wid*32 + mi*16 + (lane>>4)*4 + j;
                recipZ[(size_t)bh*2048 + krow] = 1.0f / v;
            }
        }
}

// ---------------- scale V rows by recipZ:  vT[bh][d][s] *= rZ[bh][s] ----------------
__global__ __launch_bounds__(256) void k_scaleV(u16* __restrict__ vT, const float* __restrict__ rZ){
    int stride = gridDim.x * blockDim.x;
    for (int g = blockIdx.x * blockDim.x + threadIdx.x; g < 64*64*256; g += stride){
        int s8 = g & 255;
        int bh = g >> 14;
        const float* rp = rZ + ((size_t)bh << 11) + s8*8;
        float4 r0 = *(const float4*)rp;
        float4 r1 = *(const float4*)(rp + 4);
        union { u16 s[8]; uint4 u; } v;
        v.u = *(const uint4*)(vT + (size_t)g*8);
        v.s[0] = f2bf(bf2f(v.s[0]) * r0.x);
        v.s[1] = f2bf(bf2f(v.s[1]) * r0.y);
        v.s[2] = f2bf(bf2f(v.s[2]) * r0.z);
        v.s[3] = f2bf(bf2f(v.s[3]) * r0.w);
        v.s[4] = f2bf(bf2f(v.s[4]) * r1.x);
        v.s[5] = f2bf(bf2f(v.s[5]) * r1.y);
        v.s[6] = f2bf(bf2f(v.s[6]) * r1.z);
        v.s[7] = f2bf(bf2f(v.s[7]) * r1.w);
        *(uint4*)(vT + (size_t)g*8) = v.u;
    }
}

// ---------------- Pass B: out[q,d] = sum_k exp(SCALE*q.k) * (rz*v)[k,d] ----------------
// Swapped QK^T: z' = mfma(K,Q) -> lane holds S[k][q] with q = lane&15.
// P assembled into PV A-fragments fully in-register via permlane swaps.
__global__ __launch_bounds__(256) void k_passB(
    const u16* __restrict__ qh, const u16* __restrict__ kh, const u16* __restrict__ vT,
    u16* __restrict__ Zbf)
{
    __shared__ __align__(16) u16 q_lds[128*64];   // 16KB
    __shared__ __align__(16) u16 k_lds[128*64];   // 16KB
    __shared__ __align__(16) u16 v_lds[64*128];   // 16KB  -> 48KB total, 3 blocks/CU
    const int lane = threadIdx.x & 63, wid = threadIdx.x >> 6;
    const int qb = blockIdx.x, bh = blockIdx.y;

    // stage q block once
    #pragma unroll
    for (int cc = 0; cc < 4; ++cc){
        int c = wid*4 + cc;
        int row = c*8 + (lane>>3);
        int inner = (lane&7)*16;
        gload16((const char*)(qh + ((size_t)bh*2048 + qb*128 + row)*64) + (inner ^ ((row&7)<<4)),
                (char*)q_lds + c*1024);
    }

    f32x4 acc[2][4] = {};
    bf16x8 aq[2][2];

    for (int kt = 0; kt < 16; ++kt){
        __syncthreads();   // prior k_lds/v_lds reads done
        #pragma unroll
        for (int cc = 0; cc < 4; ++cc){
            int c = wid*4 + cc;
            int row = c*8 + (lane>>3);
            int inner = (lane&7)*16;
            gload16((const char*)(kh + ((size_t)bh*2048 + kt*128 + row)*64) + (inner ^ ((row&7)<<4)),
                    (char*)k_lds + c*1024);
        }
        #pragma unroll
        for (int cc = 0; cc < 4; ++cc){
            int c = wid*4 + cc;
            int d = c*4 + (lane>>4);
            int inner = (lane&15)*16;
            gload16((const char*)(vT + ((size_t)bh*64 + d)*2048 + kt*128) + (inner ^ ((d&7)<<4)),
                    (char*)v_lds + c*1024);
        }
        __syncthreads();
        if (kt == 0){
            #pragma unroll
            for (int mi = 0; mi < 2; ++mi)
                #pragma unroll
                for (int kk = 0; kk < 2; ++kk){
                    int row = wid*32 + mi*16 + (lane & 15);
                    aq[mi][kk] = *(const bf16x8*)((const char*)q_lds + row*128
                                  + ((kk*64 + (lane>>4)*16) ^ ((row&7)<<4)));
                }
        }
        #pragma unroll
        for (int kk = 0; kk < 4; ++kk){
            // V fragments for this 32-k slice (B operand, rows = d)
            bf16x8 bv[4];
            #pragma unroll
            for (int nj = 0; nj < 4; ++nj){
                int d = nj*16 + (lane & 15);
                bv[nj] = *(const bf16x8*)((const char*)v_lds + d*256
                           + ((kk*64 + (lane>>4)*16) ^ ((d&7)<<4)));
            }
            // K fragments (A operand) for the two 16-k tiles of this slice
            bf16x8 bkt[2][2];
            #pragma unroll
            for (int t = 0; t < 2; ++t){
                int row = (kk*2 + t)*16 + (lane & 15);
                int base = row*128, sw = (row&7)<<4;
                bkt[t][0] = *(const bf16x8*)((const char*)k_lds + base + (((lane>>4)*16) ^ sw));
                bkt[t][1] = *(const bf16x8*)((const char*)k_lds + base + ((64 + (lane>>4)*16) ^ sw));
            }
            #pragma unroll
            for (int mi = 0; mi < 2; ++mi){
                // swapped QK^T: C[k][q], q = lane&15, k = tile*16 + (lane>>4)*4 + j
                f32x4 z0 = {}, z1 = {};
                z0 = __builtin_amdgcn_mfma_f32_16x16x32_bf16(bkt[0][0], aq[mi][0], z0, 0,0,0);
                z0 = __builtin_amdgcn_mfma_f32_16x16x32_bf16(bkt[0][1], aq[mi][1], z0, 0,0,0);
                z1 = __builtin_amdgcn_mfma_f32_16x16x32_bf16(bkt[1][0], aq[mi][0], z1, 0,0,0);
                z1 = __builtin_amdgcn_mfma_f32_16x16x32_bf16(bkt[1][1], aq[mi][1], z1, 0,0,0);
                // exp + pack bf16 pairs (k ascending within u32)
                unsigned u0 = f2bf(__expf(z0[0]*SCALE)) | ((unsigned)f2bf(__expf(z0[1]*SCALE)) << 16);
                unsigned u1 = f2bf(__expf(z0[2]*SCALE)) | ((unsigned)f2bf(__expf(z0[3]*SCALE)) << 16);
                unsigned w0 = f2bf(__expf(z1[0]*SCALE)) | ((unsigned)f2bf(__expf(z1[1]*SCALE)) << 16);
                unsigned w1 = f2bf(__expf(z1[2]*SCALE)) | ((unsigned)f2bf(__expf(z1[3]*SCALE)) << 16);
                // [u0..]=k 4g+{0,1} tile0, [w0..]=tile1; assemble A-frag words:
                // after p32+p16: u0=[g0,g2|g0,g2] = k 8g+{0,1}; w0 = k 8g+{4,5}; u1/w1 = {2,3}/{6,7}
                plswap32(u0, w0); plswap16(u0, w0);
                plswap32(u1, w1); plswap16(u1, w1);
                union { uint4 ui; bf16x8 v8; } ap;
                ap.ui.x = u0; ap.ui.y = u1; ap.ui.z = w0; ap.ui.w = w1;
                #pragma unroll
                for (int nj = 0; nj < 4; ++nj)
                    acc[mi][nj] = __builtin_amdgcn_mfma_f32_16x16x32_bf16(ap.v8, bv[nj], acc[mi][nj], 0,0,0);
            }
        }
    }
    // epilogue -> merged-head bf16 [b*2048+q][h*64+d]
    const int b = bh >> 4, h = bh & 15;
    #pragma unroll
    for (int mi = 0; mi < 2; ++mi)
        #pragma unroll
        for (int nj = 0; nj < 4; ++nj)
            #pragma unroll
            for (int j = 0; j < 4; ++j){
                int qrow = qb*128 + wid*32 + mi*16 + (lane>>4)*4 + j;
                int d = nj*16 + (lane & 15);
                Zbf[((size_t)b*2048 + qrow)*1024 + h*64 + d] = f2bf(acc[mi][nj][j]);
            }
}

extern "C" void kernel_launch(void* const* d_in, const int* in_sizes, int n_in,
                              void* d_out, int out_size, void* d_ws, size_t ws_size,
                              hipStream_t stream)
{
    const float* x  = (const float*)d_in[0];
    const float* Wq = (const float*)d_in[1];
    const float* Wk = (const float*)d_in[2];
    const float* Wv = (const float*)d_in[3];
    const float* Wo = (const float*)d_in[4];

    char* ws = (char*)d_ws;
    u16*   xbf  = (u16*)ws;                       // 16 MB; reused later as Zbf
    u16*   wqkv = (u16*)(ws + (16u<<20));         //  6 MB
    u16*   wobf = (u16*)(ws + (22u<<20));         //  2 MB
    u16*   vT   = (u16*)(ws + (24u<<20));         // 16 MB [64 bh][64 dh][2048 s]
    float* rZ   = (float*)(ws + (40u<<20));       // 0.5 MB [64][2048]
    u16*   Zbf  = xbf;

    u16* qh = (u16*)d_out;                        // 16 MB [64 bh][2048 s][64 dh]
    u16* kh = (u16*)d_out + (size_t)8192*1024;    // 16 MB

    k_cvt<<<1024, 256, 0, stream>>>(x,  xbf,  8192*1024/8);
    k_cvt<<<256,  256, 0, stream>>>(Wq, wqkv,               1024*1024/8);
    k_cvt<<<256,  256, 0, stream>>>(Wk, wqkv + 1024*1024,   1024*1024/8);
    k_cvt<<<256,  256, 0, stream>>>(Wv, wqkv + 2*1024*1024, 1024*1024/8);
    k_cvt<<<256,  256, 0, stream>>>(Wo, wobf,               1024*1024/8);

    k_gemm<1><<<dim3(24, 64), 256, 0, stream>>>(xbf, wqkv, nullptr, qh, kh, vT, 1024, 3072);

    k_passA<<<dim3(16, 64), 256, 0, stream>>>(qh, kh, rZ);

    k_scaleV<<<2048, 256, 0, stream>>>(vT, rZ);

    k_passB<<<dim3(16, 64), 256, 0, stream>>>(qh, kh, vT, Zbf);

    k_gemm<0><<<dim3(8, 64), 256, 0, stream>>>(Zbf, wobf, (float*)d_out,
                                               nullptr, nullptr, nullptr, 1024, 1024);
}